// Round 6
// baseline (48.674 us; speedup 1.0000x reference)
//
#include <hip/hip_runtime.h>

#define NG  4000
#define EPG 512

// ---- prep: p = W1*(W2*(W3*1)); out[0..63]=p, out[64]=b1.q2, out[65]=b2.w3, out[66]=64*sum(b3)
__global__ __launch_bounds__(256) void prep_vec(
    const float* __restrict__ W1, const float* __restrict__ b1,
    const float* __restrict__ W2, const float* __restrict__ b2,
    const float* __restrict__ W3, const float* __restrict__ b3,
    float* __restrict__ out)
{
    __shared__ float M[4096];
    __shared__ float w3[64], q2[64];
    const int t = threadIdx.x;
    const int row = t >> 2, q = t & 3;

    for (int i = t; i < 1024; i += 256) ((float4*)M)[i] = ((const float4*)W3)[i];
    __syncthreads();
    {
        float acc = 0.f;
        #pragma unroll
        for (int i = 0; i < 16; ++i) acc += M[row * 64 + q * 16 + i];
        acc += __shfl_down(acc, 2, 4);
        acc += __shfl_down(acc, 1, 4);
        if (q == 0) w3[row] = acc;
    }
    __syncthreads();

    for (int i = t; i < 1024; i += 256) ((float4*)M)[i] = ((const float4*)W2)[i];
    __syncthreads();
    {
        float acc = 0.f;
        #pragma unroll
        for (int i = 0; i < 16; ++i) {
            const int c = q * 16 + i;
            acc += M[row * 64 + c] * w3[c];
        }
        acc += __shfl_down(acc, 2, 4);
        acc += __shfl_down(acc, 1, 4);
        if (q == 0) q2[row] = acc;
    }
    __syncthreads();

    for (int i = t; i < 1024; i += 256) ((float4*)M)[i] = ((const float4*)W1)[i];
    __syncthreads();
    {
        float acc = 0.f;
        #pragma unroll
        for (int i = 0; i < 16; ++i) {
            const int c = q * 16 + i;
            acc += M[row * 64 + c] * q2[c];
        }
        acc += __shfl_down(acc, 2, 4);
        acc += __shfl_down(acc, 1, 4);
        if (q == 0) out[row] = acc;
    }

    if (t < 64) {
        float t1 = b1[t] * q2[t];
        float t2 = b2[t] * w3[t];
        float t3 = b3[t];
        #pragma unroll
        for (int off = 32; off > 0; off >>= 1) {
            t1 += __shfl_down(t1, off, 64);
            t2 += __shfl_down(t2, off, 64);
            t3 += __shfl_down(t3, off, 64);
        }
        if (t == 0) { out[64] = t1; out[65] = t2; out[66] = 64.f * t3; }
    }
}

// ---- main: one wave per graph, no block barriers ----
__global__ __launch_bounds__(256, 4) void gcn3_wave(
    const float* __restrict__ x, const int* __restrict__ ei,
    const float* __restrict__ pv, float* __restrict__ y, int etot)
{
    __shared__ float s_zd [4][64];
    __shared__ float s_acc[4][64];
    __shared__ int   s_deg[4][64];
    __shared__ float s_p  [4][64];

    const int t = threadIdx.x, w = t >> 6, lane = t & 63;
    const int g = blockIdx.x * 4 + w;
    const int base = g * 64;

    float* zd  = s_zd [w];
    float* acc = s_acc[w];
    int*   deg = s_deg[w];
    float* pl  = s_p  [w];

    // ---- issue all global loads up front (coalesced) ----
    const float4* xg = (const float4*)(x + (size_t)g * 4096);
    float4 xr[16];
    #pragma unroll
    for (int k = 0; k < 16; ++k) xr[k] = xg[lane + 64 * k];   // 1 KB/instr per wave

    const int4* sp = (const int4*)(ei + (size_t)g * EPG);
    const int4* dp = (const int4*)(ei + (size_t)etot + (size_t)g * EPG);
    const int4 sA = sp[lane], sB = sp[lane + 64];
    const int4 dA = dp[lane], dB = dp[lane + 64];

    pl[lane]  = pv[lane];
    deg[lane] = 0;

    int se[8], de[8];
    se[0] = sA.x - base; se[1] = sA.y - base; se[2] = sA.z - base; se[3] = sA.w - base;
    se[4] = sB.x - base; se[5] = sB.y - base; se[6] = sB.z - base; se[7] = sB.w - base;
    de[0] = dA.x - base; de[1] = dA.y - base; de[2] = dA.z - base; de[3] = dA.w - base;
    de[4] = dB.x - base; de[5] = dB.y - base; de[6] = dB.z - base; de[7] = dB.w - base;

    // ---- degree (wave-private int atomics; in-order LDS pipe => read-after ok) ----
    #pragma unroll
    for (int e = 0; e < 8; ++e) atomicAdd(&deg[de[e]], 1);
    const float dr = rsqrtf((float)(deg[lane] + 1));   // +1 self-loop

    // ---- three u-passes: u[s] = dr[s]*sum_{e:(s,d)} dr[d]*zprev[d] + dr[s]^2*zprev[s]
    float zprev = 1.f;
    float u1, u2, u3;
    #pragma unroll
    for (int pass = 0; pass < 3; ++pass) {
        zd[lane]  = dr * zprev;
        acc[lane] = 0.f;
        #pragma unroll
        for (int e = 0; e < 8; ++e)
            atomicAdd(&acc[se[e]], zd[de[e]]);         // wave-private scatter
        const float u = dr * acc[lane] + dr * dr * zprev;
        if (pass == 0) u1 = u; else if (pass == 1) u2 = u; else u3 = u;
        zprev = u;
    }

    // ---- contraction: sum_r u3[r] * dot(x[r,:], p), transposed register layout ----
    zd[lane] = u3;                                     // reuse zd as u3 broadcast
    const float4 p4 = *(const float4*)&pl[(lane & 15) * 4];
    float partial = 0.f;
    #pragma unroll
    for (int k = 0; k < 16; ++k) {
        // float4 (lane + 64k) -> row = (lane>>4) + 4k, cols (lane&15)*4..+3
        const float u3v = zd[(lane >> 4) + 4 * k];
        partial += u3v * (xr[k].x * p4.x + xr[k].y * p4.y +
                          xr[k].z * p4.z + xr[k].w * p4.w);
    }

    // ---- wave reduce r, s1, s2 ----
    float r = partial, a1 = u1, a2 = u2;
    #pragma unroll
    for (int off = 32; off > 0; off >>= 1) {
        r  += __shfl_down(r,  off, 64);
        a1 += __shfl_down(a1, off, 64);
        a2 += __shfl_down(a2, off, 64);
    }
    if (lane == 0) {
        const float beta1 = pv[64], beta2 = pv[65], beta3 = pv[66];
        y[g] = (r + a2 * beta1 + a1 * beta2 + beta3) * (1.0f / 4096.0f);
    }
}

extern "C" void kernel_launch(void* const* d_in, const int* in_sizes, int n_in,
                              void* d_out, int out_size, void* d_ws, size_t ws_size,
                              hipStream_t stream) {
    const float* x  = (const float*)d_in[0];
    const int*   ei = (const int*)  d_in[1];
    const float* W1 = (const float*)d_in[2];
    const float* b1 = (const float*)d_in[3];
    const float* W2 = (const float*)d_in[4];
    const float* b2 = (const float*)d_in[5];
    const float* W3 = (const float*)d_in[6];
    const float* b3 = (const float*)d_in[7];
    float* y = (float*)d_out;
    const int etot = in_sizes[1] / 2;     // 2,048,000

    float* pv = (float*)d_ws;             // 67 floats
    hipLaunchKernelGGL(prep_vec, dim3(1), dim3(256), 0, stream,
                       W1, b1, W2, b2, W3, b3, pv);
    hipLaunchKernelGGL(gcn3_wave, dim3(NG / 4), dim3(256), 0, stream,
                       x, ei, pv, y, etot);
}